// Round 4
// baseline (1389.337 us; speedup 1.0000x reference)
//
#include <hip/hip_runtime.h>
#include <math.h>

#define NVERT 6890
#define NBATCH 1024
#define V3 20670         // NVERT*3
#define NPAD 20736       // 162*128
#define KPAD 224         // 207 pose + 10 shape + 7 zero
#define NSLICE 8
#define SLICE_V 864
#define BT2 8            // batches per block in skinning
#define VPT 2            // vertices per thread in skinning

// workspace layout (float offsets)
#define WS_SJP 0                 // NSLICE*792
#define WS_SJF 6336              // 792
#define WS_A   8192              // 1024*384 fp32 A'
#define WS_PFT 401408            // fp16 PF-ext [1024][224]
#define WS_PDT 516096            // fp16 PD-ext [20736][224]

typedef _Float16 half8 __attribute__((ext_vector_type(8)));
typedef float f32x4 __attribute__((ext_vector_type(4)));

// ---------------------------------------------------------------------------
// K0: partial reductions of SJ/JT over vertex slices. grid (24, 8) x 256
// ---------------------------------------------------------------------------
__global__ __launch_bounds__(256) void k0_joint_reduce(
    const float* __restrict__ v_template,
    const float* __restrict__ shapedirs,
    const float* __restrict__ J_regressor,
    float* __restrict__ ws)
{
    int j = blockIdx.x;
    int s = blockIdx.y;
    int t = threadIdx.x;
    int lane = t & 63, wid = t >> 6;
    int v0 = s * SLICE_V;
    int v1 = v0 + SLICE_V; if (v1 > NVERT) v1 = NVERT;

    float acc[33];
#pragma unroll
    for (int i = 0; i < 33; ++i) acc[i] = 0.f;

    for (int v = v0 + t; v < v1; v += 256) {
        float jr = J_regressor[v * 24 + j];
        const float* vp = v_template + v * 3;
        acc[30] = fmaf(vp[0], jr, acc[30]);
        acc[31] = fmaf(vp[1], jr, acc[31]);
        acc[32] = fmaf(vp[2], jr, acc[32]);
#pragma unroll
        for (int k = 0; k < 10; ++k) {
            const float* p = shapedirs + k * V3 + v * 3;
            acc[k * 3 + 0] = fmaf(p[0], jr, acc[k * 3 + 0]);
            acc[k * 3 + 1] = fmaf(p[1], jr, acc[k * 3 + 1]);
            acc[k * 3 + 2] = fmaf(p[2], jr, acc[k * 3 + 2]);
        }
    }

#pragma unroll
    for (int i = 0; i < 33; ++i) {
#pragma unroll
        for (int o = 32; o > 0; o >>= 1)
            acc[i] += __shfl_xor(acc[i], o, 64);
    }

    __shared__ float part[4][33];
    if (lane == 0) {
#pragma unroll
        for (int i = 0; i < 33; ++i) part[wid][i] = acc[i];
    }
    __syncthreads();
    if (t < 33) {
        float r = part[0][t] + part[1][t] + part[2][t] + part[3][t];
        int k = t / 3, c = t % 3;
        int off = (k < 10) ? (WS_SJP + s * 792 + k * 72 + j * 3 + c)
                           : (WS_SJP + s * 792 + 720 + j * 3 + c);
        ws[off] = r;
    }
}

__global__ __launch_bounds__(256) void k0b_sum(float* __restrict__ ws)
{
    int i = blockIdx.x * 256 + threadIdx.x;
    if (i < 792) {
        float r = 0.f;
#pragma unroll
        for (int s = 0; s < NSLICE; ++s) r += ws[WS_SJP + s * 792 + i];
        ws[WS_SJF + i] = r;
    }
}

// ---------------------------------------------------------------------------
// C0: build PDt fp16 [NPAD][KPAD] = transpose of [posedirs ; shapedirs ; 0]
// ---------------------------------------------------------------------------
__global__ __launch_bounds__(256) void c0_convert(
    const float* __restrict__ posedirs,
    const float* __restrict__ shapedirs,
    float* __restrict__ ws)
{
    _Float16* pdt = (_Float16*)(ws + WS_PDT);
    int k = threadIdx.x;
    int n0 = blockIdx.x * 64;
    if (k >= KPAD) return;

    const float* src = nullptr;
    if (k < 207)      src = posedirs + (size_t)k * V3;
    else if (k < 217) src = shapedirs + (size_t)(k - 207) * V3;

    for (int i = 0; i < 64; ++i) {
        int n = n0 + i;
        float val = (src && n < V3) ? src[n] : 0.f;
        pdt[(size_t)n * KPAD + k] = (_Float16)val;
    }
}

// ---------------------------------------------------------------------------
// K1: Rodrigues + J + kinematic chain -> A' (fp32) and PF-ext (fp16).
// ---------------------------------------------------------------------------
__global__ __launch_bounds__(256) void k1_pose(
    const float* __restrict__ theta,
    const float* __restrict__ beta,
    float* __restrict__ ws)
{
    int t = threadIdx.x;
    int lane = t & 63, wid = t >> 6;
    int b = blockIdx.x * 4 + wid;

    __shared__ float Rs[4][24][9];
    __shared__ float Jl[4][24][3];
    __shared__ float res[4][24][16];
    __shared__ float Ai[4][16];

    if (lane < 24) {
        float tx = theta[b * 72 + lane * 3 + 0];
        float ty = theta[b * 72 + lane * 3 + 1];
        float tz = theta[b * 72 + lane * 3 + 2];
        float ax = tx + 1e-8f, ay = ty + 1e-8f, az = tz + 1e-8f;
        float ang = sqrtf(ax * ax + ay * ay + az * az);
        float h = 0.5f * ang;
        float cw = cosf(h), sw = sinf(h);
        float qw = cw;
        float qx = sw * (tx / ang);
        float qy = sw * (ty / ang);
        float qz = sw * (tz / ang);
        float qn = sqrtf(qw * qw + qx * qx + qy * qy + qz * qz);
        qw /= qn; qx /= qn; qy /= qn; qz /= qn;
        float w2 = qw * qw, x2 = qx * qx, y2 = qy * qy, z2 = qz * qz;
        float wx = qw * qx, wy = qw * qy, wz = qw * qz;
        float xy = qx * qy, xz = qx * qz, yz = qy * qz;
        Rs[wid][lane][0] = w2 + x2 - y2 - z2;
        Rs[wid][lane][1] = 2.f * xy - 2.f * wz;
        Rs[wid][lane][2] = 2.f * wy + 2.f * xz;
        Rs[wid][lane][3] = 2.f * wz + 2.f * xy;
        Rs[wid][lane][4] = w2 - x2 + y2 - z2;
        Rs[wid][lane][5] = 2.f * yz - 2.f * wx;
        Rs[wid][lane][6] = 2.f * xz - 2.f * wy;
        Rs[wid][lane][7] = 2.f * wx + 2.f * yz;
        Rs[wid][lane][8] = w2 - x2 - y2 + z2;
    }

    // J = JT + beta @ SJ
    for (int i = lane; i < 72; i += 64) {
        float sacc = ws[WS_SJF + 720 + i];
#pragma unroll
        for (int k = 0; k < 10; ++k)
            sacc = fmaf(beta[b * 10 + k], ws[WS_SJF + k * 72 + i], sacc);
        Jl[wid][i / 3][i % 3] = sacc;
    }

    // PF-ext fp16: [pf(207) | beta(10) | 0]
    {
        _Float16* pft = (_Float16*)(ws + WS_PFT);
        for (int i = lane; i < KPAD; i += 64) {
            float val;
            if (i < 207) {
                int jj = 1 + i / 9, e = i % 9;
                float sub = (e == 0 || e == 4 || e == 8) ? 1.f : 0.f;
                val = Rs[wid][jj][e] - sub;
            } else if (i < 217) {
                val = beta[b * 10 + (i - 207)];
            } else val = 0.f;
            pft[(size_t)b * KPAD + i] = (_Float16)val;
        }
    }

    if (lane < 16) {
        int r = lane >> 2, c = lane & 3;
        res[wid][0][lane] = (r < 3) ? (c < 3 ? Rs[wid][0][r * 3 + c] : Jl[wid][0][r])
                                    : (c == 3 ? 1.f : 0.f);
    }

    const int PAR[24] = {-1,0,0,0,1,2,3,4,5,6,7,8,9,9,9,12,13,14,16,17,18,19,20,21};
#pragma unroll
    for (int i = 1; i < 24; ++i) {
        int p = PAR[i];
        if (lane < 16) {
            int r = lane >> 2, c = lane & 3;
            Ai[wid][lane] = (r < 3) ? (c < 3 ? Rs[wid][i][r * 3 + c]
                                             : (Jl[wid][i][r] - Jl[wid][p][r]))
                                    : (c == 3 ? 1.f : 0.f);
            float sacc = 0.f;
#pragma unroll
            for (int k = 0; k < 4; ++k)
                sacc = fmaf(res[wid][p][r * 4 + k], Ai[wid][k * 4 + c], sacc);
            res[wid][i][lane] = sacc;
        }
    }

    for (int i = lane; i < 384; i += 64) {
        int jj = i >> 4, rc = i & 15, r = rc >> 2, cc = rc & 3;
        float val = res[wid][jj][rc];
        if (cc == 3 && r < 3) {
            val -= res[wid][jj][r * 4 + 0] * Jl[wid][jj][0]
                 + res[wid][jj][r * 4 + 1] * Jl[wid][jj][1]
                 + res[wid][jj][r * 4 + 2] * Jl[wid][jj][2];
        }
        ws[WS_A + b * 384 + i] = val;
    }
}

// ---------------------------------------------------------------------------
// K2: fp16 MFMA GEMM: out[1024][20670] = PF-ext @ PD-ext^T + v_template[cc]
// grid (162 n-tiles, 8 m-tiles) x 256
// ---------------------------------------------------------------------------
__global__ __launch_bounds__(256, 2) void k2_gemm(
    const float* __restrict__ ws,
    const float* __restrict__ v_template,
    float* __restrict__ out)
{
    const _Float16* Ap = (const _Float16*)(ws + WS_PFT);
    const _Float16* Bp = (const _Float16*)(ws + WS_PDT);
    int lane = threadIdx.x & 63, wv = threadIdx.x >> 6;
    int rowA = lane & 15;
    int kg   = lane >> 4;
    int m0 = blockIdx.y * 128;
    int n0 = blockIdx.x * 128 + wv * 32;

    f32x4 acc[8][2];
#pragma unroll
    for (int mi = 0; mi < 8; ++mi)
#pragma unroll
        for (int ni = 0; ni < 2; ++ni)
            acc[mi][ni] = (f32x4){0.f, 0.f, 0.f, 0.f};

#pragma unroll 2
    for (int ks = 0; ks < 7; ++ks) {
        int koff = ks * 32 + kg * 8;
        half8 bfrag[2];
#pragma unroll
        for (int ni = 0; ni < 2; ++ni)
            bfrag[ni] = *(const half8*)(Bp + (size_t)(n0 + ni * 16 + rowA) * KPAD + koff);
        half8 afrag[8];
#pragma unroll
        for (int mi = 0; mi < 8; ++mi)
            afrag[mi] = *(const half8*)(Ap + (size_t)(m0 + mi * 16 + rowA) * KPAD + koff);
#pragma unroll
        for (int mi = 0; mi < 8; ++mi)
#pragma unroll
            for (int ni = 0; ni < 2; ++ni)
                acc[mi][ni] = __builtin_amdgcn_mfma_f32_16x16x32_f16(
                    afrag[mi], bfrag[ni], acc[mi][ni], 0, 0, 0);
    }

#pragma unroll
    for (int ni = 0; ni < 2; ++ni) {
        int cc = n0 + ni * 16 + rowA;
        if (cc < V3) {
            float vt = v_template[cc];
#pragma unroll
            for (int mi = 0; mi < 8; ++mi) {
                int rbase = m0 + mi * 16 + kg * 4;
#pragma unroll
                for (int r = 0; r < 4; ++r)
                    out[(size_t)(rbase + r) * V3 + cc] = acc[mi][ni][r] + vt;
            }
        }
    }
}

// ---------------------------------------------------------------------------
// K3: in-place skinning on d_out. thread = vertex (coalesced), VPT=2,
// BT2=8 batches per block with A' in LDS (broadcast reads).
// grid: (ceil(NVERT/512)=14, NBATCH/BT2=128) x 256
// ---------------------------------------------------------------------------
__global__ __launch_bounds__(256, 2) void k3_skin(
    const float* __restrict__ weights,
    const float* __restrict__ ws,
    float* out)
{
    __shared__ float A_s[BT2][384];
    int t = threadIdx.x;
    int chunk = blockIdx.x, bg = blockIdx.y;

    for (int i = t; i < BT2 * 384; i += 256) {
        int bi = i / 384, e = i - bi * 384;
        A_s[bi][e] = ws[WS_A + (bg * BT2 + bi) * 384 + e];
    }
    __syncthreads();

    // per-thread vertices (stride 256) and their weights in regs
    int v[VPT];
    float w[VPT][24];
#pragma unroll
    for (int p = 0; p < VPT; ++p) {
        int vl = chunk * (256 * VPT) + p * 256 + t;
        v[p] = (vl < NVERT) ? vl : -1;
        int vcl = (vl < NVERT) ? vl : (NVERT - 1);
        const float4* wr = (const float4*)(weights + vcl * 24);
#pragma unroll
        for (int q = 0; q < 6; ++q) {
            float4 wq = wr[q];
            w[p][q * 4 + 0] = wq.x;
            w[p][q * 4 + 1] = wq.y;
            w[p][q * 4 + 2] = wq.z;
            w[p][q * 4 + 3] = wq.w;
        }
    }

    for (int bt = 0; bt < BT2; ++bt) {
        float* ob = out + (size_t)(bg * BT2 + bt) * V3;

        float px[VPT], py[VPT], pz[VPT];
#pragma unroll
        for (int p = 0; p < VPT; ++p) {
            int vcl = (v[p] >= 0) ? v[p] : (NVERT - 1);
            const float* pp = ob + vcl * 3;
            px[p] = pp[0]; py[p] = pp[1]; pz[p] = pp[2];
        }

        float M[VPT][12];
#pragma unroll
        for (int p = 0; p < VPT; ++p)
#pragma unroll
            for (int e = 0; e < 12; ++e) M[p][e] = 0.f;

        const f32x4* ar = (const f32x4*)(&A_s[bt][0]);
#pragma unroll
        for (int j = 0; j < 24; ++j) {
            f32x4 r0 = ar[j * 4 + 0];
            f32x4 r1 = ar[j * 4 + 1];
            f32x4 r2 = ar[j * 4 + 2];
#pragma unroll
            for (int p = 0; p < VPT; ++p) {
                float wj = w[p][j];
                M[p][0] = fmaf(wj, r0[0], M[p][0]);
                M[p][1] = fmaf(wj, r0[1], M[p][1]);
                M[p][2] = fmaf(wj, r0[2], M[p][2]);
                M[p][3] = fmaf(wj, r0[3], M[p][3]);
                M[p][4] = fmaf(wj, r1[0], M[p][4]);
                M[p][5] = fmaf(wj, r1[1], M[p][5]);
                M[p][6] = fmaf(wj, r1[2], M[p][6]);
                M[p][7] = fmaf(wj, r1[3], M[p][7]);
                M[p][8]  = fmaf(wj, r2[0], M[p][8]);
                M[p][9]  = fmaf(wj, r2[1], M[p][9]);
                M[p][10] = fmaf(wj, r2[2], M[p][10]);
                M[p][11] = fmaf(wj, r2[3], M[p][11]);
            }
        }

#pragma unroll
        for (int p = 0; p < VPT; ++p) {
            if (v[p] >= 0) {
                float x = px[p], y = py[p], z = pz[p];
                float o0 = fmaf(M[p][0], x, fmaf(M[p][1], y, fmaf(M[p][2],  z, M[p][3])));
                float o1 = fmaf(M[p][4], x, fmaf(M[p][5], y, fmaf(M[p][6],  z, M[p][7])));
                float o2 = fmaf(M[p][8], x, fmaf(M[p][9], y, fmaf(M[p][10], z, M[p][11])));
                float* po = ob + v[p] * 3;
                po[0] = o0; po[1] = o1; po[2] = o2;
            }
        }
    }
}

extern "C" void kernel_launch(void* const* d_in, const int* in_sizes, int n_in,
                              void* d_out, int out_size, void* d_ws, size_t ws_size,
                              hipStream_t stream) {
    const float* theta       = (const float*)d_in[0];
    const float* beta        = (const float*)d_in[1];
    const float* v_template  = (const float*)d_in[2];
    const float* shapedirs   = (const float*)d_in[3];
    const float* posedirs    = (const float*)d_in[4];
    const float* J_regressor = (const float*)d_in[5];
    const float* weights     = (const float*)d_in[6];
    float* out = (float*)d_out;
    float* ws  = (float*)d_ws;

    hipLaunchKernelGGL(k0_joint_reduce, dim3(24, NSLICE), dim3(256), 0, stream,
                       v_template, shapedirs, J_regressor, ws);
    hipLaunchKernelGGL(k0b_sum, dim3(4), dim3(256), 0, stream, ws);
    hipLaunchKernelGGL(c0_convert, dim3(324), dim3(256), 0, stream,
                       posedirs, shapedirs, ws);
    hipLaunchKernelGGL(k1_pose, dim3(NBATCH / 4), dim3(256), 0, stream,
                       theta, beta, ws);
    hipLaunchKernelGGL(k2_gemm, dim3(NPAD / 128, NBATCH / 128), dim3(256), 0, stream,
                       ws, v_template, out);
    hipLaunchKernelGGL(k3_skin, dim3((NVERT + 256 * VPT - 1) / (256 * VPT), NBATCH / BT2),
                       dim3(256), 0, stream, weights, ws, out);
}

// Round 6
// 1271.950 us; speedup vs baseline: 1.0923x; 1.0923x over previous
//
#include <hip/hip_runtime.h>
#include <math.h>

#define NVERT 6890
#define NBATCH 1024
#define V3 20670         // NVERT*3
#define NPAD 20736       // 162*128
#define KPAD 224         // 207 pose + 10 shape + 7 zero
#define NSLICE 8
#define SLICE_V 864
#define BT2 8            // batches per block in skinning

// workspace layout (float offsets)
#define WS_SJP 0                 // NSLICE*792
#define WS_SJF 6336              // 792
#define WS_A   8192              // 1024*384 fp32 A'
#define WS_PFT 401408            // fp16 PF-ext [1024][224]
#define WS_PDT 516096            // fp16 PD-ext [20736][224]
#define WS_VP  2838528           // fp16 v_posed [1024][V3]  (10,583,040 f-slots)

typedef _Float16 half8 __attribute__((ext_vector_type(8)));
typedef _Float16 half2v __attribute__((ext_vector_type(2)));
typedef float f32x4 __attribute__((ext_vector_type(4)));

// ---------------------------------------------------------------------------
// K0: partial reductions of SJ/JT over vertex slices. grid (24, 8) x 256
// ---------------------------------------------------------------------------
__global__ __launch_bounds__(256) void k0_joint_reduce(
    const float* __restrict__ v_template,
    const float* __restrict__ shapedirs,
    const float* __restrict__ J_regressor,
    float* __restrict__ ws)
{
    int j = blockIdx.x;
    int s = blockIdx.y;
    int t = threadIdx.x;
    int lane = t & 63, wid = t >> 6;
    int v0 = s * SLICE_V;
    int v1 = v0 + SLICE_V; if (v1 > NVERT) v1 = NVERT;

    float acc[33];
#pragma unroll
    for (int i = 0; i < 33; ++i) acc[i] = 0.f;

    for (int v = v0 + t; v < v1; v += 256) {
        float jr = J_regressor[v * 24 + j];
        const float* vp = v_template + v * 3;
        acc[30] = fmaf(vp[0], jr, acc[30]);
        acc[31] = fmaf(vp[1], jr, acc[31]);
        acc[32] = fmaf(vp[2], jr, acc[32]);
#pragma unroll
        for (int k = 0; k < 10; ++k) {
            const float* p = shapedirs + k * V3 + v * 3;
            acc[k * 3 + 0] = fmaf(p[0], jr, acc[k * 3 + 0]);
            acc[k * 3 + 1] = fmaf(p[1], jr, acc[k * 3 + 1]);
            acc[k * 3 + 2] = fmaf(p[2], jr, acc[k * 3 + 2]);
        }
    }

#pragma unroll
    for (int i = 0; i < 33; ++i) {
#pragma unroll
        for (int o = 32; o > 0; o >>= 1)
            acc[i] += __shfl_xor(acc[i], o, 64);
    }

    __shared__ float part[4][33];
    if (lane == 0) {
#pragma unroll
        for (int i = 0; i < 33; ++i) part[wid][i] = acc[i];
    }
    __syncthreads();
    if (t < 33) {
        float r = part[0][t] + part[1][t] + part[2][t] + part[3][t];
        int k = t / 3, c = t % 3;
        int off = (k < 10) ? (WS_SJP + s * 792 + k * 72 + j * 3 + c)
                           : (WS_SJP + s * 792 + 720 + j * 3 + c);
        ws[off] = r;
    }
}

__global__ __launch_bounds__(256) void k0b_sum(float* __restrict__ ws)
{
    int i = blockIdx.x * 256 + threadIdx.x;
    if (i < 792) {
        float r = 0.f;
#pragma unroll
        for (int s = 0; s < NSLICE; ++s) r += ws[WS_SJP + s * 792 + i];
        ws[WS_SJF + i] = r;
    }
}

// ---------------------------------------------------------------------------
// C0: build PDt fp16 [NPAD][KPAD] = transpose of [posedirs ; shapedirs ; 0]
// ---------------------------------------------------------------------------
__global__ __launch_bounds__(256) void c0_convert(
    const float* __restrict__ posedirs,
    const float* __restrict__ shapedirs,
    float* __restrict__ ws)
{
    _Float16* pdt = (_Float16*)(ws + WS_PDT);
    int k = threadIdx.x;
    int n0 = blockIdx.x * 64;
    if (k >= KPAD) return;

    const float* src = nullptr;
    if (k < 207)      src = posedirs + (size_t)k * V3;
    else if (k < 217) src = shapedirs + (size_t)(k - 207) * V3;

    for (int i = 0; i < 64; ++i) {
        int n = n0 + i;
        float val = (src && n < V3) ? src[n] : 0.f;
        pdt[(size_t)n * KPAD + k] = (_Float16)val;
    }
}

// ---------------------------------------------------------------------------
// K1: Rodrigues + J + kinematic chain -> A' (fp32) and PF-ext (fp16).
// ---------------------------------------------------------------------------
__global__ __launch_bounds__(256) void k1_pose(
    const float* __restrict__ theta,
    const float* __restrict__ beta,
    float* __restrict__ ws)
{
    int t = threadIdx.x;
    int lane = t & 63, wid = t >> 6;
    int b = blockIdx.x * 4 + wid;

    __shared__ float Rs[4][24][9];
    __shared__ float Jl[4][24][3];
    __shared__ float res[4][24][16];
    __shared__ float Ai[4][16];

    if (lane < 24) {
        float tx = theta[b * 72 + lane * 3 + 0];
        float ty = theta[b * 72 + lane * 3 + 1];
        float tz = theta[b * 72 + lane * 3 + 2];
        float ax = tx + 1e-8f, ay = ty + 1e-8f, az = tz + 1e-8f;
        float ang = sqrtf(ax * ax + ay * ay + az * az);
        float h = 0.5f * ang;
        float cw = cosf(h), sw = sinf(h);
        float qw = cw;
        float qx = sw * (tx / ang);
        float qy = sw * (ty / ang);
        float qz = sw * (tz / ang);
        float qn = sqrtf(qw * qw + qx * qx + qy * qy + qz * qz);
        qw /= qn; qx /= qn; qy /= qn; qz /= qn;
        float w2 = qw * qw, x2 = qx * qx, y2 = qy * qy, z2 = qz * qz;
        float wx = qw * qx, wy = qw * qy, wz = qw * qz;
        float xy = qx * qy, xz = qx * qz, yz = qy * qz;
        Rs[wid][lane][0] = w2 + x2 - y2 - z2;
        Rs[wid][lane][1] = 2.f * xy - 2.f * wz;
        Rs[wid][lane][2] = 2.f * wy + 2.f * xz;
        Rs[wid][lane][3] = 2.f * wz + 2.f * xy;
        Rs[wid][lane][4] = w2 - x2 + y2 - z2;
        Rs[wid][lane][5] = 2.f * yz - 2.f * wx;
        Rs[wid][lane][6] = 2.f * xz - 2.f * wy;
        Rs[wid][lane][7] = 2.f * wx + 2.f * yz;
        Rs[wid][lane][8] = w2 - x2 - y2 + z2;
    }

    // J = JT + beta @ SJ
    for (int i = lane; i < 72; i += 64) {
        float sacc = ws[WS_SJF + 720 + i];
#pragma unroll
        for (int k = 0; k < 10; ++k)
            sacc = fmaf(beta[b * 10 + k], ws[WS_SJF + k * 72 + i], sacc);
        Jl[wid][i / 3][i % 3] = sacc;
    }

    // PF-ext fp16: [pf(207) | beta(10) | 0]
    {
        _Float16* pft = (_Float16*)(ws + WS_PFT);
        for (int i = lane; i < KPAD; i += 64) {
            float val;
            if (i < 207) {
                int jj = 1 + i / 9, e = i % 9;
                float sub = (e == 0 || e == 4 || e == 8) ? 1.f : 0.f;
                val = Rs[wid][jj][e] - sub;
            } else if (i < 217) {
                val = beta[b * 10 + (i - 207)];
            } else val = 0.f;
            pft[(size_t)b * KPAD + i] = (_Float16)val;
        }
    }

    if (lane < 16) {
        int r = lane >> 2, c = lane & 3;
        res[wid][0][lane] = (r < 3) ? (c < 3 ? Rs[wid][0][r * 3 + c] : Jl[wid][0][r])
                                    : (c == 3 ? 1.f : 0.f);
    }

    const int PAR[24] = {-1,0,0,0,1,2,3,4,5,6,7,8,9,9,9,12,13,14,16,17,18,19,20,21};
#pragma unroll
    for (int i = 1; i < 24; ++i) {
        int p = PAR[i];
        if (lane < 16) {
            int r = lane >> 2, c = lane & 3;
            Ai[wid][lane] = (r < 3) ? (c < 3 ? Rs[wid][i][r * 3 + c]
                                             : (Jl[wid][i][r] - Jl[wid][p][r]))
                                    : (c == 3 ? 1.f : 0.f);
            float sacc = 0.f;
#pragma unroll
            for (int k = 0; k < 4; ++k)
                sacc = fmaf(res[wid][p][r * 4 + k], Ai[wid][k * 4 + c], sacc);
            res[wid][i][lane] = sacc;
        }
    }

    for (int i = lane; i < 384; i += 64) {
        int jj = i >> 4, rc = i & 15, r = rc >> 2, cc = rc & 3;
        float val = res[wid][jj][rc];
        if (cc == 3 && r < 3) {
            val -= res[wid][jj][r * 4 + 0] * Jl[wid][jj][0]
                 + res[wid][jj][r * 4 + 1] * Jl[wid][jj][1]
                 + res[wid][jj][r * 4 + 2] * Jl[wid][jj][2];
        }
        ws[WS_A + b * 384 + i] = val;
    }
}

// ---------------------------------------------------------------------------
// K2: fp16 MFMA GEMM: v_posed[1024][V3] (fp16, in ws) = PF-ext @ PD-ext^T + vt
// grid (162 n-tiles, 8 m-tiles) x 256
// ---------------------------------------------------------------------------
__global__ __launch_bounds__(256, 2) void k2_gemm(
    const float* __restrict__ ws_ro,
    const float* __restrict__ v_template,
    float* __restrict__ ws)
{
    const _Float16* Ap = (const _Float16*)(ws_ro + WS_PFT);
    const _Float16* Bp = (const _Float16*)(ws_ro + WS_PDT);
    _Float16* vpw = (_Float16*)(ws + WS_VP);
    int lane = threadIdx.x & 63, wv = threadIdx.x >> 6;
    int rowA = lane & 15;
    int kg   = lane >> 4;
    int m0 = blockIdx.y * 128;
    int n0 = blockIdx.x * 128 + wv * 32;

    f32x4 acc[8][2];
#pragma unroll
    for (int mi = 0; mi < 8; ++mi)
#pragma unroll
        for (int ni = 0; ni < 2; ++ni)
            acc[mi][ni] = (f32x4){0.f, 0.f, 0.f, 0.f};

#pragma unroll 2
    for (int ks = 0; ks < 7; ++ks) {
        int koff = ks * 32 + kg * 8;
        half8 bfrag[2];
#pragma unroll
        for (int ni = 0; ni < 2; ++ni)
            bfrag[ni] = *(const half8*)(Bp + (size_t)(n0 + ni * 16 + rowA) * KPAD + koff);
        half8 afrag[8];
#pragma unroll
        for (int mi = 0; mi < 8; ++mi)
            afrag[mi] = *(const half8*)(Ap + (size_t)(m0 + mi * 16 + rowA) * KPAD + koff);
#pragma unroll
        for (int mi = 0; mi < 8; ++mi)
#pragma unroll
            for (int ni = 0; ni < 2; ++ni)
                acc[mi][ni] = __builtin_amdgcn_mfma_f32_16x16x32_f16(
                    afrag[mi], bfrag[ni], acc[mi][ni], 0, 0, 0);
    }

#pragma unroll
    for (int ni = 0; ni < 2; ++ni) {
        int cc = n0 + ni * 16 + rowA;
        if (cc < V3) {
            float vt = v_template[cc];
#pragma unroll
            for (int mi = 0; mi < 8; ++mi) {
                int rbase = m0 + mi * 16 + kg * 4;
#pragma unroll
                for (int r = 0; r < 4; ++r)
                    vpw[(size_t)(rbase + r) * V3 + cc] = (_Float16)(acc[mi][ni][r] + vt);
            }
        }
    }
}

// ---------------------------------------------------------------------------
// K3: skinning, WRITE-ONCE to d_out (never reads it). thread = 2 adjacent
// vertices; reads fp16 v_posed from ws; A' broadcast from LDS.
// grid: (ceil(NVERT/512)=14, NBATCH/BT2=128) x 256
// ---------------------------------------------------------------------------
__global__ __launch_bounds__(256, 2) void k3_skin(
    const float* __restrict__ weights,
    const float* __restrict__ ws,
    float* __restrict__ out)
{
    __shared__ float A_s[BT2][384];
    int t = threadIdx.x;
    int chunk = blockIdx.x, bg = blockIdx.y;

    for (int i = t; i < BT2 * 384; i += 256) {
        int bi = i / 384, e = i - bi * 384;
        A_s[bi][e] = ws[WS_A + (bg * BT2 + bi) * 384 + e];
    }
    __syncthreads();

    const _Float16* vp = (const _Float16*)(ws + WS_VP);

    int v0 = chunk * 512 + 2 * t;          // this thread's two vertices
    bool ok0 = v0 < NVERT, ok1 = (v0 + 1) < NVERT;
    int vc0 = ok0 ? v0 : (NVERT - 1);
    int vc1 = ok1 ? (v0 + 1) : (NVERT - 1);

    // weights for both vertices in regs (contiguous 192B per thread)
    float w0[24], w1[24];
    {
        const float4* wr0 = (const float4*)(weights + vc0 * 24);
        const float4* wr1 = (const float4*)(weights + vc1 * 24);
#pragma unroll
        for (int q = 0; q < 6; ++q) {
            float4 a = wr0[q], b = wr1[q];
            w0[q * 4 + 0] = a.x; w0[q * 4 + 1] = a.y;
            w0[q * 4 + 2] = a.z; w0[q * 4 + 3] = a.w;
            w1[q * 4 + 0] = b.x; w1[q * 4 + 1] = b.y;
            w1[q * 4 + 2] = b.z; w1[q * 4 + 3] = b.w;
        }
    }

    for (int bt = 0; bt < BT2; ++bt) {
        int b = bg * BT2 + bt;
        const _Float16* vb = vp + (size_t)b * V3;

        float x0, y0, z0, x1, y1, z1;
        if (ok1) {
            // 12B contiguous, 4B-aligned (v0 even): three half2 loads
            half2v p01 = *(const half2v*)(vb + v0 * 3 + 0);
            half2v p23 = *(const half2v*)(vb + v0 * 3 + 2);
            half2v p45 = *(const half2v*)(vb + v0 * 3 + 4);
            x0 = (float)p01[0]; y0 = (float)p01[1];
            z0 = (float)p23[0]; x1 = (float)p23[1];
            y1 = (float)p45[0]; z1 = (float)p45[1];
        } else {
            x0 = (float)vb[vc0 * 3 + 0]; y0 = (float)vb[vc0 * 3 + 1];
            z0 = (float)vb[vc0 * 3 + 2];
            x1 = (float)vb[vc1 * 3 + 0]; y1 = (float)vb[vc1 * 3 + 1];
            z1 = (float)vb[vc1 * 3 + 2];
        }

        float M0[12], M1[12];
#pragma unroll
        for (int e = 0; e < 12; ++e) { M0[e] = 0.f; M1[e] = 0.f; }

        const f32x4* ar = (const f32x4*)(&A_s[bt][0]);
#pragma unroll
        for (int j = 0; j < 24; ++j) {
            f32x4 r0 = ar[j * 4 + 0];
            f32x4 r1 = ar[j * 4 + 1];
            f32x4 r2 = ar[j * 4 + 2];
            float wa = w0[j], wb = w1[j];
            M0[0] = fmaf(wa, r0[0], M0[0]);  M1[0] = fmaf(wb, r0[0], M1[0]);
            M0[1] = fmaf(wa, r0[1], M0[1]);  M1[1] = fmaf(wb, r0[1], M1[1]);
            M0[2] = fmaf(wa, r0[2], M0[2]);  M1[2] = fmaf(wb, r0[2], M1[2]);
            M0[3] = fmaf(wa, r0[3], M0[3]);  M1[3] = fmaf(wb, r0[3], M1[3]);
            M0[4] = fmaf(wa, r1[0], M0[4]);  M1[4] = fmaf(wb, r1[0], M1[4]);
            M0[5] = fmaf(wa, r1[1], M0[5]);  M1[5] = fmaf(wb, r1[1], M1[5]);
            M0[6] = fmaf(wa, r1[2], M0[6]);  M1[6] = fmaf(wb, r1[2], M1[6]);
            M0[7] = fmaf(wa, r1[3], M0[7]);  M1[7] = fmaf(wb, r1[3], M1[7]);
            M0[8]  = fmaf(wa, r2[0], M0[8]);   M1[8]  = fmaf(wb, r2[0], M1[8]);
            M0[9]  = fmaf(wa, r2[1], M0[9]);   M1[9]  = fmaf(wb, r2[1], M1[9]);
            M0[10] = fmaf(wa, r2[2], M0[10]);  M1[10] = fmaf(wb, r2[2], M1[10]);
            M0[11] = fmaf(wa, r2[3], M0[11]);  M1[11] = fmaf(wb, r2[3], M1[11]);
        }

        float* ob = out + (size_t)b * V3;
        if (ok0) {
            float* po = ob + v0 * 3;
            po[0] = fmaf(M0[0], x0, fmaf(M0[1], y0, fmaf(M0[2],  z0, M0[3])));
            po[1] = fmaf(M0[4], x0, fmaf(M0[5], y0, fmaf(M0[6],  z0, M0[7])));
            po[2] = fmaf(M0[8], x0, fmaf(M0[9], y0, fmaf(M0[10], z0, M0[11])));
        }
        if (ok1) {
            float* po = ob + v0 * 3 + 3;
            po[0] = fmaf(M1[0], x1, fmaf(M1[1], y1, fmaf(M1[2],  z1, M1[3])));
            po[1] = fmaf(M1[4], x1, fmaf(M1[5], y1, fmaf(M1[6],  z1, M1[7])));
            po[2] = fmaf(M1[8], x1, fmaf(M1[9], y1, fmaf(M1[10], z1, M1[11])));
        }
    }
}

extern "C" void kernel_launch(void* const* d_in, const int* in_sizes, int n_in,
                              void* d_out, int out_size, void* d_ws, size_t ws_size,
                              hipStream_t stream) {
    const float* theta       = (const float*)d_in[0];
    const float* beta        = (const float*)d_in[1];
    const float* v_template  = (const float*)d_in[2];
    const float* shapedirs   = (const float*)d_in[3];
    const float* posedirs    = (const float*)d_in[4];
    const float* J_regressor = (const float*)d_in[5];
    const float* weights     = (const float*)d_in[6];
    float* out = (float*)d_out;
    float* ws  = (float*)d_ws;

    hipLaunchKernelGGL(k0_joint_reduce, dim3(24, NSLICE), dim3(256), 0, stream,
                       v_template, shapedirs, J_regressor, ws);
    hipLaunchKernelGGL(k0b_sum, dim3(4), dim3(256), 0, stream, ws);
    hipLaunchKernelGGL(c0_convert, dim3(324), dim3(256), 0, stream,
                       posedirs, shapedirs, ws);
    hipLaunchKernelGGL(k1_pose, dim3(NBATCH / 4), dim3(256), 0, stream,
                       theta, beta, ws);
    hipLaunchKernelGGL(k2_gemm, dim3(NPAD / 128, NBATCH / 128), dim3(256), 0, stream,
                       ws, v_template, ws);
    hipLaunchKernelGGL(k3_skin, dim3((NVERT + 511) / 512, NBATCH / BT2),
                       dim3(256), 0, stream, weights, ws, out);
}

// Round 7
// 421.208 us; speedup vs baseline: 3.2985x; 3.0198x over previous
//
#include <hip/hip_runtime.h>
#include <math.h>

#define NVERT 6890
#define NBATCH 1024
#define V3 20670         // NVERT*3
#define NPAD 20736       // 216*96
#define KPAD 224         // 207 pose + 10 shape + 7 zero
#define NSLICE 8
#define SLICE_V 864

// workspace layout (float offsets)
#define WS_SJP 0                 // NSLICE*792
#define WS_SJF 6336              // 792
#define WS_A   8192              // 1024*384 fp32 A'
#define WS_PFT 401408            // fp16 PF-ext [1024][224]
#define WS_PDT 516096            // fp16 PD-ext [20736][224]

typedef _Float16 half8 __attribute__((ext_vector_type(8)));
typedef float f32x4 __attribute__((ext_vector_type(4)));

// ---------------------------------------------------------------------------
// K0: partial reductions of SJ/JT over vertex slices. grid (24, 8) x 256
// ---------------------------------------------------------------------------
__global__ __launch_bounds__(256) void k0_joint_reduce(
    const float* __restrict__ v_template,
    const float* __restrict__ shapedirs,
    const float* __restrict__ J_regressor,
    float* __restrict__ ws)
{
    int j = blockIdx.x;
    int s = blockIdx.y;
    int t = threadIdx.x;
    int lane = t & 63, wid = t >> 6;
    int v0 = s * SLICE_V;
    int v1 = v0 + SLICE_V; if (v1 > NVERT) v1 = NVERT;

    float acc[33];
#pragma unroll
    for (int i = 0; i < 33; ++i) acc[i] = 0.f;

    for (int v = v0 + t; v < v1; v += 256) {
        float jr = J_regressor[v * 24 + j];
        const float* vp = v_template + v * 3;
        acc[30] = fmaf(vp[0], jr, acc[30]);
        acc[31] = fmaf(vp[1], jr, acc[31]);
        acc[32] = fmaf(vp[2], jr, acc[32]);
#pragma unroll
        for (int k = 0; k < 10; ++k) {
            const float* p = shapedirs + k * V3 + v * 3;
            acc[k * 3 + 0] = fmaf(p[0], jr, acc[k * 3 + 0]);
            acc[k * 3 + 1] = fmaf(p[1], jr, acc[k * 3 + 1]);
            acc[k * 3 + 2] = fmaf(p[2], jr, acc[k * 3 + 2]);
        }
    }

#pragma unroll
    for (int i = 0; i < 33; ++i) {
#pragma unroll
        for (int o = 32; o > 0; o >>= 1)
            acc[i] += __shfl_xor(acc[i], o, 64);
    }

    __shared__ float part[4][33];
    if (lane == 0) {
#pragma unroll
        for (int i = 0; i < 33; ++i) part[wid][i] = acc[i];
    }
    __syncthreads();
    if (t < 33) {
        float r = part[0][t] + part[1][t] + part[2][t] + part[3][t];
        int k = t / 3, c = t % 3;
        int off = (k < 10) ? (WS_SJP + s * 792 + k * 72 + j * 3 + c)
                           : (WS_SJP + s * 792 + 720 + j * 3 + c);
        ws[off] = r;
    }
}

__global__ __launch_bounds__(256) void k0b_sum(float* __restrict__ ws)
{
    int i = blockIdx.x * 256 + threadIdx.x;
    if (i < 792) {
        float r = 0.f;
#pragma unroll
        for (int s = 0; s < NSLICE; ++s) r += ws[WS_SJP + s * 792 + i];
        ws[WS_SJF + i] = r;
    }
}

// ---------------------------------------------------------------------------
// C0: build PDt fp16 [NPAD][KPAD] via LDS transpose (coalesced both sides).
// grid 324 (n-chunks of 64) x 256
// ---------------------------------------------------------------------------
__global__ __launch_bounds__(256) void c0_convert(
    const float* __restrict__ posedirs,
    const float* __restrict__ shapedirs,
    float* __restrict__ ws)
{
    __shared__ float S[56][65];
    _Float16* pdt = (_Float16*)(ws + WS_PDT);
    int t = threadIdx.x;
    int n0 = blockIdx.x * 64;

    for (int kc = 0; kc < 4; ++kc) {
        for (int i = t; i < 56 * 64; i += 256) {
            int r = i >> 6, c = i & 63;
            int k = kc * 56 + r;
            int n = n0 + c;
            float val = 0.f;
            if (n < V3) {
                if (k < 207)      val = posedirs[(size_t)k * V3 + n];
                else if (k < 217) val = shapedirs[(size_t)(k - 207) * V3 + n];
            }
            S[r][c] = val;
        }
        __syncthreads();
        for (int i = t; i < 64 * 56; i += 256) {
            int nn = i / 56, kk = i - nn * 56;
            pdt[(size_t)(n0 + nn) * KPAD + kc * 56 + kk] = (_Float16)S[kk][nn];
        }
        __syncthreads();
    }
}

// ---------------------------------------------------------------------------
// K1: Rodrigues + J + kinematic chain -> A' (fp32) and PF-ext (fp16).
// ---------------------------------------------------------------------------
__global__ __launch_bounds__(256) void k1_pose(
    const float* __restrict__ theta,
    const float* __restrict__ beta,
    float* __restrict__ ws)
{
    int t = threadIdx.x;
    int lane = t & 63, wid = t >> 6;
    int b = blockIdx.x * 4 + wid;

    __shared__ float Rs[4][24][9];
    __shared__ float Jl[4][24][3];
    __shared__ float res[4][24][16];
    __shared__ float Ai[4][16];

    if (lane < 24) {
        float tx = theta[b * 72 + lane * 3 + 0];
        float ty = theta[b * 72 + lane * 3 + 1];
        float tz = theta[b * 72 + lane * 3 + 2];
        float ax = tx + 1e-8f, ay = ty + 1e-8f, az = tz + 1e-8f;
        float ang = sqrtf(ax * ax + ay * ay + az * az);
        float h = 0.5f * ang;
        float cw = cosf(h), sw = sinf(h);
        float qw = cw;
        float qx = sw * (tx / ang);
        float qy = sw * (ty / ang);
        float qz = sw * (tz / ang);
        float qn = sqrtf(qw * qw + qx * qx + qy * qy + qz * qz);
        qw /= qn; qx /= qn; qy /= qn; qz /= qn;
        float w2 = qw * qw, x2 = qx * qx, y2 = qy * qy, z2 = qz * qz;
        float wx = qw * qx, wy = qw * qy, wz = qw * qz;
        float xy = qx * qy, xz = qx * qz, yz = qy * qz;
        Rs[wid][lane][0] = w2 + x2 - y2 - z2;
        Rs[wid][lane][1] = 2.f * xy - 2.f * wz;
        Rs[wid][lane][2] = 2.f * wy + 2.f * xz;
        Rs[wid][lane][3] = 2.f * wz + 2.f * xy;
        Rs[wid][lane][4] = w2 - x2 + y2 - z2;
        Rs[wid][lane][5] = 2.f * yz - 2.f * wx;
        Rs[wid][lane][6] = 2.f * xz - 2.f * wy;
        Rs[wid][lane][7] = 2.f * wx + 2.f * yz;
        Rs[wid][lane][8] = w2 - x2 - y2 + z2;
    }

    // J = JT + beta @ SJ
    for (int i = lane; i < 72; i += 64) {
        float sacc = ws[WS_SJF + 720 + i];
#pragma unroll
        for (int k = 0; k < 10; ++k)
            sacc = fmaf(beta[b * 10 + k], ws[WS_SJF + k * 72 + i], sacc);
        Jl[wid][i / 3][i % 3] = sacc;
    }

    // PF-ext fp16: [pf(207) | beta(10) | 0]
    {
        _Float16* pft = (_Float16*)(ws + WS_PFT);
        for (int i = lane; i < KPAD; i += 64) {
            float val;
            if (i < 207) {
                int jj = 1 + i / 9, e = i % 9;
                float sub = (e == 0 || e == 4 || e == 8) ? 1.f : 0.f;
                val = Rs[wid][jj][e] - sub;
            } else if (i < 217) {
                val = beta[b * 10 + (i - 207)];
            } else val = 0.f;
            pft[(size_t)b * KPAD + i] = (_Float16)val;
        }
    }

    if (lane < 16) {
        int r = lane >> 2, c = lane & 3;
        res[wid][0][lane] = (r < 3) ? (c < 3 ? Rs[wid][0][r * 3 + c] : Jl[wid][0][r])
                                    : (c == 3 ? 1.f : 0.f);
    }

    const int PAR[24] = {-1,0,0,0,1,2,3,4,5,6,7,8,9,9,9,12,13,14,16,17,18,19,20,21};
#pragma unroll
    for (int i = 1; i < 24; ++i) {
        int p = PAR[i];
        if (lane < 16) {
            int r = lane >> 2, c = lane & 3;
            Ai[wid][lane] = (r < 3) ? (c < 3 ? Rs[wid][i][r * 3 + c]
                                             : (Jl[wid][i][r] - Jl[wid][p][r]))
                                    : (c == 3 ? 1.f : 0.f);
            float sacc = 0.f;
#pragma unroll
            for (int k = 0; k < 4; ++k)
                sacc = fmaf(res[wid][p][r * 4 + k], Ai[wid][k * 4 + c], sacc);
            res[wid][i][lane] = sacc;
        }
    }

    for (int i = lane; i < 384; i += 64) {
        int jj = i >> 4, rc = i & 15, r = rc >> 2, cc = rc & 3;
        float val = res[wid][jj][rc];
        if (cc == 3 && r < 3) {
            val -= res[wid][jj][r * 4 + 0] * Jl[wid][jj][0]
                 + res[wid][jj][r * 4 + 1] * Jl[wid][jj][1]
                 + res[wid][jj][r * 4 + 2] * Jl[wid][jj][2];
        }
        ws[WS_A + b * 384 + i] = val;
    }
}

// ---------------------------------------------------------------------------
// K2_FUSED: GEMM (BM=32 batches x BN=96 coords = 32 whole vertices)
//           + in-LDS skinning + single coalesced write of d_out.
// No large intermediate ever touches global memory.
// grid (32 m-tiles, 216 n-tiles) x 256
// ---------------------------------------------------------------------------
__global__ __launch_bounds__(256) void k2_fused(
    const float* __restrict__ ws,
    const float* __restrict__ v_template,
    const float* __restrict__ weights,
    float* __restrict__ out)
{
    __shared__ float p_s[32][100];   // v_posed tile (pad 100: conflict-free)
    __shared__ float A_s[32][292];   // A' rows 0..2 per joint (12 floats x 24 j)
    __shared__ float w_s[32][25];    // weights (pad 25: 25 coprime 32)

    int t = threadIdx.x;
    int m0 = blockIdx.x * 32;        // batch base
    int nt = blockIdx.y;
    int n0 = nt * 96;                // coord base
    int vbase = nt * 32;             // vertex base

    // stage A' (rows 0..2 of each 4x4, i.e. first 12 of 16 floats per joint)
    for (int i = t; i < 32 * 288; i += 256) {
        int bi = i / 288, e = i - bi * 288;
        int j = e / 12, rc = e - j * 12;
        A_s[bi][e] = ws[WS_A + (m0 + bi) * 384 + j * 16 + rc];
    }
    // stage weights
    for (int i = t; i < 32 * 24; i += 256) {
        int vi = i / 24, j = i - vi * 24;
        int vg = vbase + vi; if (vg > NVERT - 1) vg = NVERT - 1;
        w_s[vi][j] = weights[vg * 24 + j];
    }

    // ---- GEMM: 4 waves = 2 (m-halves of 16) x 2 (n-halves of 48) ----
    const _Float16* Ap = (const _Float16*)(ws + WS_PFT);
    const _Float16* Bp = (const _Float16*)(ws + WS_PDT);
    int lane = t & 63, wv = t >> 6;
    int rowA = lane & 15, kg = lane >> 4;
    int mh = wv & 1, nh = wv >> 1;

    f32x4 acc[3];
#pragma unroll
    for (int ni = 0; ni < 3; ++ni) acc[ni] = (f32x4){0.f, 0.f, 0.f, 0.f};

#pragma unroll
    for (int ks = 0; ks < 7; ++ks) {
        int koff = ks * 32 + kg * 8;
        half8 af = *(const half8*)(Ap + (size_t)(m0 + mh * 16 + rowA) * KPAD + koff);
        half8 bf[3];
#pragma unroll
        for (int ni = 0; ni < 3; ++ni)
            bf[ni] = *(const half8*)(Bp + (size_t)(n0 + nh * 48 + ni * 16 + rowA) * KPAD + koff);
#pragma unroll
        for (int ni = 0; ni < 3; ++ni)
            acc[ni] = __builtin_amdgcn_mfma_f32_16x16x32_f16(af, bf[ni], acc[ni], 0, 0, 0);
    }

    // v_posed tile -> LDS (add v_template here)
#pragma unroll
    for (int ni = 0; ni < 3; ++ni) {
        int cc = n0 + nh * 48 + ni * 16 + rowA;
        int ccc = cc < V3 ? cc : (V3 - 1);
        float vt = v_template[ccc];
#pragma unroll
        for (int r = 0; r < 4; ++r)
            p_s[mh * 16 + kg * 4 + r][nh * 48 + ni * 16 + rowA] = acc[ni][r] + vt;
    }

    __syncthreads();

    // ---- skinning: thread = (vertex v = t&31, batch-quad bq = t>>5) ----
    int v = t & 31, bq = t >> 5;

    float px[4][3];
#pragma unroll
    for (int bb = 0; bb < 4; ++bb) {
#pragma unroll
        for (int d = 0; d < 3; ++d)
            px[bb][d] = p_s[bq * 4 + bb][3 * v + d];
    }

    float o[12];
#pragma unroll
    for (int e = 0; e < 12; ++e) o[e] = 0.f;

#pragma unroll
    for (int j = 0; j < 24; ++j) {
        float wj = w_s[v][j];
#pragma unroll
        for (int bb = 0; bb < 4; ++bb) {
            const f32x4* ar = (const f32x4*)(&A_s[bq * 4 + bb][j * 12]);
            float x = px[bb][0], y = px[bb][1], z = px[bb][2];
#pragma unroll
            for (int d = 0; d < 3; ++d) {
                f32x4 r = ar[d];
                float dotv = fmaf(r[0], x, fmaf(r[1], y, fmaf(r[2], z, r[3])));
                o[bb * 3 + d] = fmaf(wj, dotv, o[bb * 3 + d]);
            }
        }
    }

    int gv = vbase + v;
    if (gv < NVERT) {
#pragma unroll
        for (int bb = 0; bb < 4; ++bb) {
            float* po = out + (size_t)(m0 + bq * 4 + bb) * V3 + gv * 3;
            po[0] = o[bb * 3 + 0];
            po[1] = o[bb * 3 + 1];
            po[2] = o[bb * 3 + 2];
        }
    }
}

extern "C" void kernel_launch(void* const* d_in, const int* in_sizes, int n_in,
                              void* d_out, int out_size, void* d_ws, size_t ws_size,
                              hipStream_t stream) {
    const float* theta       = (const float*)d_in[0];
    const float* beta        = (const float*)d_in[1];
    const float* v_template  = (const float*)d_in[2];
    const float* shapedirs   = (const float*)d_in[3];
    const float* posedirs    = (const float*)d_in[4];
    const float* J_regressor = (const float*)d_in[5];
    const float* weights     = (const float*)d_in[6];
    float* out = (float*)d_out;
    float* ws  = (float*)d_ws;

    hipLaunchKernelGGL(k0_joint_reduce, dim3(24, NSLICE), dim3(256), 0, stream,
                       v_template, shapedirs, J_regressor, ws);
    hipLaunchKernelGGL(k0b_sum, dim3(4), dim3(256), 0, stream, ws);
    hipLaunchKernelGGL(c0_convert, dim3(NPAD / 64), dim3(256), 0, stream,
                       posedirs, shapedirs, ws);
    hipLaunchKernelGGL(k1_pose, dim3(NBATCH / 4), dim3(256), 0, stream,
                       theta, beta, ws);
    hipLaunchKernelGGL(k2_fused, dim3(NBATCH / 32, NPAD / 96), dim3(256), 0, stream,
                       ws, v_template, weights, out);
}

// Round 8
// 395.306 us; speedup vs baseline: 3.5146x; 1.0655x over previous
//
#include <hip/hip_runtime.h>
#include <math.h>

#define NVERT 6890
#define NBATCH 1024
#define V3 20670         // NVERT*3
#define NPAD 20736       // 216*96
#define KPAD 224         // 207 pose + 10 shape + 7 zero
#define NSLICE 8
#define SLICE_V 864

// workspace layout (float offsets)
#define WS_SJP 0                 // NSLICE*792
#define WS_SJF 6336              // 792
#define WS_A   8192              // 1024*384 fp32 A'
#define WS_PFT 401408            // fp16 PF-ext [1024][224]
#define WS_PDT 516096            // fp16 PD-ext [20736][224]

typedef _Float16 half8 __attribute__((ext_vector_type(8)));
typedef float f32x4 __attribute__((ext_vector_type(4)));

// ---------------------------------------------------------------------------
// K0: partial reductions of SJ/JT over vertex slices. grid (24, 8) x 256
// ---------------------------------------------------------------------------
__global__ __launch_bounds__(256) void k0_joint_reduce(
    const float* __restrict__ v_template,
    const float* __restrict__ shapedirs,
    const float* __restrict__ J_regressor,
    float* __restrict__ ws)
{
    int j = blockIdx.x;
    int s = blockIdx.y;
    int t = threadIdx.x;
    int lane = t & 63, wid = t >> 6;
    int v0 = s * SLICE_V;
    int v1 = v0 + SLICE_V; if (v1 > NVERT) v1 = NVERT;

    float acc[33];
#pragma unroll
    for (int i = 0; i < 33; ++i) acc[i] = 0.f;

    for (int v = v0 + t; v < v1; v += 256) {
        float jr = J_regressor[v * 24 + j];
        const float* vp = v_template + v * 3;
        acc[30] = fmaf(vp[0], jr, acc[30]);
        acc[31] = fmaf(vp[1], jr, acc[31]);
        acc[32] = fmaf(vp[2], jr, acc[32]);
#pragma unroll
        for (int k = 0; k < 10; ++k) {
            const float* p = shapedirs + k * V3 + v * 3;
            acc[k * 3 + 0] = fmaf(p[0], jr, acc[k * 3 + 0]);
            acc[k * 3 + 1] = fmaf(p[1], jr, acc[k * 3 + 1]);
            acc[k * 3 + 2] = fmaf(p[2], jr, acc[k * 3 + 2]);
        }
    }

#pragma unroll
    for (int i = 0; i < 33; ++i) {
#pragma unroll
        for (int o = 32; o > 0; o >>= 1)
            acc[i] += __shfl_xor(acc[i], o, 64);
    }

    __shared__ float part[4][33];
    if (lane == 0) {
#pragma unroll
        for (int i = 0; i < 33; ++i) part[wid][i] = acc[i];
    }
    __syncthreads();
    if (t < 33) {
        float r = part[0][t] + part[1][t] + part[2][t] + part[3][t];
        int k = t / 3, c = t % 3;
        int off = (k < 10) ? (WS_SJP + s * 792 + k * 72 + j * 3 + c)
                           : (WS_SJP + s * 792 + 720 + j * 3 + c);
        ws[off] = r;
    }
}

__global__ __launch_bounds__(256) void k0b_sum(float* __restrict__ ws)
{
    int i = blockIdx.x * 256 + threadIdx.x;
    if (i < 792) {
        float r = 0.f;
#pragma unroll
        for (int s = 0; s < NSLICE; ++s) r += ws[WS_SJP + s * 792 + i];
        ws[WS_SJF + i] = r;
    }
}

// ---------------------------------------------------------------------------
// C0: build PDt fp16 [NPAD][KPAD] via LDS transpose (coalesced both sides).
// ---------------------------------------------------------------------------
__global__ __launch_bounds__(256) void c0_convert(
    const float* __restrict__ posedirs,
    const float* __restrict__ shapedirs,
    float* __restrict__ ws)
{
    __shared__ float S[56][65];
    _Float16* pdt = (_Float16*)(ws + WS_PDT);
    int t = threadIdx.x;
    int n0 = blockIdx.x * 64;

    for (int kc = 0; kc < 4; ++kc) {
        for (int i = t; i < 56 * 64; i += 256) {
            int r = i >> 6, c = i & 63;
            int k = kc * 56 + r;
            int n = n0 + c;
            float val = 0.f;
            if (n < V3) {
                if (k < 207)      val = posedirs[(size_t)k * V3 + n];
                else if (k < 217) val = shapedirs[(size_t)(k - 207) * V3 + n];
            }
            S[r][c] = val;
        }
        __syncthreads();
        for (int i = t; i < 64 * 56; i += 256) {
            int nn = i / 56, kk = i - nn * 56;
            pdt[(size_t)(n0 + nn) * KPAD + kc * 56 + kk] = (_Float16)S[kk][nn];
        }
        __syncthreads();
    }
}

// ---------------------------------------------------------------------------
// K1: Rodrigues + J + kinematic chain -> A' (fp32) and PF-ext (fp16).
// ---------------------------------------------------------------------------
__global__ __launch_bounds__(256) void k1_pose(
    const float* __restrict__ theta,
    const float* __restrict__ beta,
    float* __restrict__ ws)
{
    int t = threadIdx.x;
    int lane = t & 63, wid = t >> 6;
    int b = blockIdx.x * 4 + wid;

    __shared__ float Rs[4][24][9];
    __shared__ float Jl[4][24][3];
    __shared__ float res[4][24][16];
    __shared__ float Ai[4][16];

    if (lane < 24) {
        float tx = theta[b * 72 + lane * 3 + 0];
        float ty = theta[b * 72 + lane * 3 + 1];
        float tz = theta[b * 72 + lane * 3 + 2];
        float ax = tx + 1e-8f, ay = ty + 1e-8f, az = tz + 1e-8f;
        float ang = sqrtf(ax * ax + ay * ay + az * az);
        float h = 0.5f * ang;
        float cw = cosf(h), sw = sinf(h);
        float qw = cw;
        float qx = sw * (tx / ang);
        float qy = sw * (ty / ang);
        float qz = sw * (tz / ang);
        float qn = sqrtf(qw * qw + qx * qx + qy * qy + qz * qz);
        qw /= qn; qx /= qn; qy /= qn; qz /= qn;
        float w2 = qw * qw, x2 = qx * qx, y2 = qy * qy, z2 = qz * qz;
        float wx = qw * qx, wy = qw * qy, wz = qw * qz;
        float xy = qx * qy, xz = qx * qz, yz = qy * qz;
        Rs[wid][lane][0] = w2 + x2 - y2 - z2;
        Rs[wid][lane][1] = 2.f * xy - 2.f * wz;
        Rs[wid][lane][2] = 2.f * wy + 2.f * xz;
        Rs[wid][lane][3] = 2.f * wz + 2.f * xy;
        Rs[wid][lane][4] = w2 - x2 + y2 - z2;
        Rs[wid][lane][5] = 2.f * yz - 2.f * wx;
        Rs[wid][lane][6] = 2.f * xz - 2.f * wy;
        Rs[wid][lane][7] = 2.f * wx + 2.f * yz;
        Rs[wid][lane][8] = w2 - x2 - y2 + z2;
    }

    // J = JT + beta @ SJ
    for (int i = lane; i < 72; i += 64) {
        float sacc = ws[WS_SJF + 720 + i];
#pragma unroll
        for (int k = 0; k < 10; ++k)
            sacc = fmaf(beta[b * 10 + k], ws[WS_SJF + k * 72 + i], sacc);
        Jl[wid][i / 3][i % 3] = sacc;
    }

    // PF-ext fp16: [pf(207) | beta(10) | 0]
    {
        _Float16* pft = (_Float16*)(ws + WS_PFT);
        for (int i = lane; i < KPAD; i += 64) {
            float val;
            if (i < 207) {
                int jj = 1 + i / 9, e = i % 9;
                float sub = (e == 0 || e == 4 || e == 8) ? 1.f : 0.f;
                val = Rs[wid][jj][e] - sub;
            } else if (i < 217) {
                val = beta[b * 10 + (i - 207)];
            } else val = 0.f;
            pft[(size_t)b * KPAD + i] = (_Float16)val;
        }
    }

    if (lane < 16) {
        int r = lane >> 2, c = lane & 3;
        res[wid][0][lane] = (r < 3) ? (c < 3 ? Rs[wid][0][r * 3 + c] : Jl[wid][0][r])
                                    : (c == 3 ? 1.f : 0.f);
    }

    const int PAR[24] = {-1,0,0,0,1,2,3,4,5,6,7,8,9,9,9,12,13,14,16,17,18,19,20,21};
#pragma unroll
    for (int i = 1; i < 24; ++i) {
        int p = PAR[i];
        if (lane < 16) {
            int r = lane >> 2, c = lane & 3;
            Ai[wid][lane] = (r < 3) ? (c < 3 ? Rs[wid][i][r * 3 + c]
                                             : (Jl[wid][i][r] - Jl[wid][p][r]))
                                    : (c == 3 ? 1.f : 0.f);
            float sacc = 0.f;
#pragma unroll
            for (int k = 0; k < 4; ++k)
                sacc = fmaf(res[wid][p][r * 4 + k], Ai[wid][k * 4 + c], sacc);
            res[wid][i][lane] = sacc;
        }
    }

    for (int i = lane; i < 384; i += 64) {
        int jj = i >> 4, rc = i & 15, r = rc >> 2, cc = rc & 3;
        float val = res[wid][jj][rc];
        if (cc == 3 && r < 3) {
            val -= res[wid][jj][r * 4 + 0] * Jl[wid][jj][0]
                 + res[wid][jj][r * 4 + 1] * Jl[wid][jj][1]
                 + res[wid][jj][r * 4 + 2] * Jl[wid][jj][2];
        }
        ws[WS_A + b * 384 + i] = val;
    }
}

// ---------------------------------------------------------------------------
// K2_FUSED: GEMM (BM=32 batches x BN=96 coords = 32 whole vertices)
//           + in-LDS skinning + single coalesced write of d_out.
// Skinning thread map: (vertex-quad vq = t&7, batch b = t>>3) so the A'-row
// LDS reads are amortized over 4 vertices (3x fewer LDS instrs than R7).
// grid (32 m-tiles, 216 n-tiles) x 256
// ---------------------------------------------------------------------------
__global__ __launch_bounds__(256) void k2_fused(
    const float* __restrict__ ws,
    const float* __restrict__ v_template,
    const float* __restrict__ weights,
    float* __restrict__ out)
{
    __shared__ float p_s[32][100];   // v_posed tile [batch][96 coords], pad 100
    __shared__ float A_s[32][292];   // [batch][24 j * 12]: rows 0..2 of A'
    __shared__ float w_s[24][32];    // weights TRANSPOSED [joint][vertex]

    int t = threadIdx.x;
    int m0 = blockIdx.x * 32;        // batch base
    int nt = blockIdx.y;
    int n0 = nt * 96;                // coord base
    int vbase = nt * 32;             // vertex base

    // stage A' (rows 0..2 of each 4x4 -> 12 floats per joint)
    for (int i = t; i < 32 * 288; i += 256) {
        int bi = i / 288, e = i - bi * 288;
        int j = e / 12, rc = e - j * 12;
        A_s[bi][e] = ws[WS_A + (m0 + bi) * 384 + j * 16 + rc];
    }
    // stage weights transposed
    for (int i = t; i < 24 * 32; i += 256) {
        int j = i >> 5, vi = i & 31;
        int vg = vbase + vi; if (vg > NVERT - 1) vg = NVERT - 1;
        w_s[j][vi] = weights[vg * 24 + j];
    }

    // ---- GEMM: 4 waves = 2 (m-halves of 16) x 2 (n-halves of 48) ----
    const _Float16* Ap = (const _Float16*)(ws + WS_PFT);
    const _Float16* Bp = (const _Float16*)(ws + WS_PDT);
    int lane = t & 63, wv = t >> 6;
    int rowA = lane & 15, kg = lane >> 4;
    int mh = wv & 1, nh = wv >> 1;

    f32x4 acc[3];
#pragma unroll
    for (int ni = 0; ni < 3; ++ni) acc[ni] = (f32x4){0.f, 0.f, 0.f, 0.f};

#pragma unroll
    for (int ks = 0; ks < 7; ++ks) {
        int koff = ks * 32 + kg * 8;
        half8 af = *(const half8*)(Ap + (size_t)(m0 + mh * 16 + rowA) * KPAD + koff);
        half8 bf[3];
#pragma unroll
        for (int ni = 0; ni < 3; ++ni)
            bf[ni] = *(const half8*)(Bp + (size_t)(n0 + nh * 48 + ni * 16 + rowA) * KPAD + koff);
#pragma unroll
        for (int ni = 0; ni < 3; ++ni)
            acc[ni] = __builtin_amdgcn_mfma_f32_16x16x32_f16(af, bf[ni], acc[ni], 0, 0, 0);
    }

    // v_posed tile -> LDS (add v_template here)
#pragma unroll
    for (int ni = 0; ni < 3; ++ni) {
        int cc = n0 + nh * 48 + ni * 16 + rowA;
        int ccc = cc < V3 ? cc : (V3 - 1);
        float vt = v_template[ccc];
#pragma unroll
        for (int r = 0; r < 4; ++r)
            p_s[mh * 16 + kg * 4 + r][nh * 48 + ni * 16 + rowA] = acc[ni][r] + vt;
    }

    __syncthreads();

    // ---- skinning: thread = (vertex-quad vq = t&7, batch b = t>>3) ----
    int vq = t & 7, b = t >> 3;

    // positions of this thread's 4 vertices in batch b: 12 consecutive floats
    const f32x4* prow = (const f32x4*)(&p_s[b][12 * vq]);
    f32x4 q0 = prow[0], q1 = prow[1], q2 = prow[2];
    float px[4], py[4], pz[4];
    px[0] = q0[0]; py[0] = q0[1]; pz[0] = q0[2];
    px[1] = q0[3]; py[1] = q1[0]; pz[1] = q1[1];
    px[2] = q1[2]; py[2] = q1[3]; pz[2] = q2[0];
    px[3] = q2[1]; py[3] = q2[2]; pz[3] = q2[3];

    float o[4][3];
#pragma unroll
    for (int vi = 0; vi < 4; ++vi)
#pragma unroll
        for (int d = 0; d < 3; ++d) o[vi][d] = 0.f;

    const f32x4* arow = (const f32x4*)(&A_s[b][0]);   // [j*3 + d]
#pragma unroll
    for (int j = 0; j < 24; ++j) {
        f32x4 r0 = arow[j * 3 + 0];
        f32x4 r1 = arow[j * 3 + 1];
        f32x4 r2 = arow[j * 3 + 2];
        f32x4 w4 = *(const f32x4*)(&w_s[j][4 * vq]);
#pragma unroll
        for (int vi = 0; vi < 4; ++vi) {
            float x = px[vi], y = py[vi], z = pz[vi];
            float d0 = fmaf(r0[0], x, fmaf(r0[1], y, fmaf(r0[2], z, r0[3])));
            float d1 = fmaf(r1[0], x, fmaf(r1[1], y, fmaf(r1[2], z, r1[3])));
            float d2 = fmaf(r2[0], x, fmaf(r2[1], y, fmaf(r2[2], z, r2[3])));
            float wj = w4[vi];
            o[vi][0] = fmaf(wj, d0, o[vi][0]);
            o[vi][1] = fmaf(wj, d1, o[vi][1]);
            o[vi][2] = fmaf(wj, d2, o[vi][2]);
        }
    }

    // write: 4 consecutive vertices of batch b -> 48B contiguous
    int gv0 = vbase + 4 * vq;
    float* po = out + (size_t)(m0 + b) * V3 + (size_t)gv0 * 3;
#pragma unroll
    for (int vi = 0; vi < 4; ++vi) {
        int gv = gv0 + vi;
        if (gv < NVERT) {
            po[vi * 3 + 0] = o[vi][0];
            po[vi * 3 + 1] = o[vi][1];
            po[vi * 3 + 2] = o[vi][2];
        }
    }
}

extern "C" void kernel_launch(void* const* d_in, const int* in_sizes, int n_in,
                              void* d_out, int out_size, void* d_ws, size_t ws_size,
                              hipStream_t stream) {
    const float* theta       = (const float*)d_in[0];
    const float* beta        = (const float*)d_in[1];
    const float* v_template  = (const float*)d_in[2];
    const float* shapedirs   = (const float*)d_in[3];
    const float* posedirs    = (const float*)d_in[4];
    const float* J_regressor = (const float*)d_in[5];
    const float* weights     = (const float*)d_in[6];
    float* out = (float*)d_out;
    float* ws  = (float*)d_ws;

    hipLaunchKernelGGL(k0_joint_reduce, dim3(24, NSLICE), dim3(256), 0, stream,
                       v_template, shapedirs, J_regressor, ws);
    hipLaunchKernelGGL(k0b_sum, dim3(4), dim3(256), 0, stream, ws);
    hipLaunchKernelGGL(c0_convert, dim3(NPAD / 64), dim3(256), 0, stream,
                       posedirs, shapedirs, ws);
    hipLaunchKernelGGL(k1_pose, dim3(NBATCH / 4), dim3(256), 0, stream,
                       theta, beta, ws);
    hipLaunchKernelGGL(k2_fused, dim3(NBATCH / 32, NPAD / 96), dim3(256), 0, stream,
                       ws, v_template, weights, out);
}